// Round 4
// baseline (1073.225 us; speedup 1.0000x reference)
//
#include <hip/hip_runtime.h>
#include <math.h>

#define D 128
#define B2D 256
#define NSEG 64
#define MAXC 512
#define PSTRIDE 144   // floats per chunk-partial: [0]=m, [1]=s, [8..135]=acc[128]
#define NBLK 1024
#define NTHR 256

// ---------------- setup: seg map (binary search, eb sorted) + chunk map +
// done-counter zeroing + closed-form first LSTM step ----------------
__global__ __launch_bounds__(128) void k_setup(
        const int* __restrict__ eb, int E,
        const float* __restrict__ b_ih, const float* __restrict__ b_hh,
        int* __restrict__ seg, int* __restrict__ pre, int* __restrict__ epw,
        int* __restrict__ done, float* __restrict__ h, float* __restrict__ c) {
    __shared__ int s_seg[NSEG + 1], s_cnt[NSEG];
    int t = threadIdx.x;   // 0..127
    if (t <= NSEG) {
        int lo = 0, hi = E;
        while (lo < hi) { int mid = (lo + hi) >> 1; if (eb[mid] < t) lo = mid + 1; else hi = mid; }
        s_seg[t] = lo; seg[t] = lo;
    }
    // zero the 3x64 done counters
    done[t] = 0; if (t < 64) done[128 + t] = 0;
    __syncthreads();
    if (t < NSEG) {
        int len = s_seg[t + 1] - s_seg[t];
        int e = 128;                          // multiple of 4: full chunks have no tail
        int cc = (len + e - 1) / e;
        if (cc > MAXC) { e = (len + MAXC - 1) / MAXC; cc = (len + e - 1) / e; }
        if (len == 0) cc = 1;                 // dummy chunk so combine still triggers
        epw[t] = e; s_cnt[t] = cc;
    }
    __syncthreads();
    if (t == 0) {
        int a = 0;
        for (int j = 0; j < NSEG; ++j) { pre[j] = a; a += s_cnt[j]; }
        pre[NSEG] = a;
    }
    // closed-form LSTM step 1: q_star=h=c=0 => gates = b_ih+b_hh (same all rows)
    float gi = b_ih[t] + b_hh[t];
    float gg = b_ih[t + 2 * D] + b_hh[t + 2 * D];
    float go = b_ih[t + 3 * D] + b_hh[t + 3 * D];
    float si = 1.f / (1.f + expf(-gi));
    float so = 1.f / (1.f + expf(-go));
    float cn = si * tanhf(gg);                // sigmoid(f)*c0 drops (c0=0)
    float hn = so * tanhf(cn);
    for (int b = 0; b < NSEG; ++b) { h[b * D + t] = hn; c[b * D + t] = cn; }
}

// ---------------- one attention iteration: pass + last-wave-per-segment
// combine + in-wave LSTM (threadfence-reduction pattern, no grid sync) --------
template <int IT>   // 0,1: combine->LSTM updates h,c   2: combine->write out
__global__ __launch_bounds__(NTHR) void k_iter(
        const float* __restrict__ feat,
        const float* __restrict__ w_ih, const float* __restrict__ w_hh,
        const float* __restrict__ b_ih, const float* __restrict__ b_hh,
        const int* __restrict__ seg, const int* __restrict__ pre,
        const int* __restrict__ epw,
        float* __restrict__ h, float* __restrict__ c,
        float* __restrict__ part, int* __restrict__ done,
        float* __restrict__ out) {
    __shared__ int s_pre[NSEG + 1], s_ofs[NSEG + 1], s_epw[NSEG];
    __shared__ float s_hx[4][D], s_rx[4][D];   // per-wave slabs for LSTM exchange
    int tid = threadIdx.x;
    if (tid <= NSEG) { s_pre[tid] = pre[tid]; s_ofs[tid] = seg[tid]; }
    if (tid < NSEG) s_epw[tid] = epw[tid];
    __syncthreads();
    int total = s_pre[NSEG];
    int gwave = (blockIdx.x * NTHR + tid) >> 6;
    int nwaves = (gridDim.x * NTHR) >> 6;
    int lane = tid & 63, half = lane >> 5, sl = lane & 31;
    int wslot = tid >> 6;

    for (int cid = gwave; cid < total; cid += nwaves) {
        // binary search: largest b with s_pre[b] <= cid
        int lo = 0, hi = NSEG - 1;
        while (lo < hi) {
            int mid = (lo + hi + 1) >> 1;
            if (s_pre[mid] <= cid) lo = mid; else hi = mid - 1;
        }
        int b = lo;
        int e = s_epw[b];
        long s0 = (long)s_ofs[b] + (long)(cid - s_pre[b]) * e;
        long s1 = (long)s_ofs[b + 1];
        long send = s0 + e;
        if (send < s1) s1 = send;

        float4 q4 = *(const float4*)(h + (size_t)b * D + sl * 4);
        float m = -INFINITY, ssum = 0.f;
        float4 acc = make_float4(0.f, 0.f, 0.f, 0.f);

        long nfull = (s1 - s0) >> 2;          // 4-edge groups
        long ee = s0 + nfull * 4;

        if (nfull > 0) {
            const float* p = feat + (size_t)(s0 + half) * D + sl * 4;
            float4 fa = *(const float4*)p;            // edges +0,+1
            float4 fb = *(const float4*)(p + 2 * D);  // edges +2,+3
            p += 4 * D;
            #pragma unroll 2
            for (long g = 0; g < nfull; ++g) {
                float4 ca = fa, cb = fb;
                if (g + 1 < nfull) {                  // prefetch next group
                    fa = *(const float4*)p;
                    fb = *(const float4*)(p + 2 * D);
                    p += 4 * D;
                }
                float pa = ca.x * q4.x + ca.y * q4.y + ca.z * q4.z + ca.w * q4.w;
                float pb = cb.x * q4.x + cb.y * q4.y + cb.z * q4.z + cb.w * q4.w;
                pa += __shfl_xor(pa, 16, 32); pb += __shfl_xor(pb, 16, 32);
                pa += __shfl_xor(pa, 8, 32);  pb += __shfl_xor(pb, 8, 32);
                pa += __shfl_xor(pa, 4, 32);  pb += __shfl_xor(pb, 4, 32);
                pa += __shfl_xor(pa, 2, 32);  pb += __shfl_xor(pb, 2, 32);
                pa += __shfl_xor(pa, 1, 32);  pb += __shfl_xor(pb, 1, 32);
                float nm = fmaxf(m, fmaxf(pa, pb));
                float sc = __expf(m - nm);            // exp(-inf)=0 on first group
                float wa = __expf(pa - nm);
                float wb = __expf(pb - nm);
                ssum = ssum * sc + wa + wb;
                acc.x = acc.x * sc + wa * ca.x + wb * cb.x;
                acc.y = acc.y * sc + wa * ca.y + wb * cb.y;
                acc.z = acc.z * sc + wa * ca.z + wb * cb.z;
                acc.w = acc.w * sc + wa * ca.w + wb * cb.w;
                m = nm;
            }
        }

        // tail: 0..3 edges, 2-wide masked
        for (; ee < s1; ee += 2) {
            long my_e = ee + half;
            bool valid = my_e < s1;
            float4 f4 = make_float4(0.f, 0.f, 0.f, 0.f);
            if (valid) f4 = *(const float4*)(feat + (size_t)my_e * D + sl * 4);
            float p = f4.x * q4.x + f4.y * q4.y + f4.z * q4.z + f4.w * q4.w;
            p += __shfl_xor(p, 16, 32);
            p += __shfl_xor(p, 8, 32);
            p += __shfl_xor(p, 4, 32);
            p += __shfl_xor(p, 2, 32);
            p += __shfl_xor(p, 1, 32);
            if (valid) {
                float nm = fmaxf(m, p);
                float sc = __expf(m - nm);
                float we = __expf(p - nm);
                ssum = ssum * sc + we;
                acc.x = acc.x * sc + we * f4.x;
                acc.y = acc.y * sc + we * f4.y;
                acc.z = acc.z * sc + we * f4.z;
                acc.w = acc.w * sc + we * f4.w;
                m = nm;
            }
        }

        // merge half-wave states (NaN-guarded for the empty-chunk -inf case)
        float m_o = __shfl_xor(m, 32);
        float s_o = __shfl_xor(ssum, 32);
        float4 a_o;
        a_o.x = __shfl_xor(acc.x, 32);
        a_o.y = __shfl_xor(acc.y, 32);
        a_o.z = __shfl_xor(acc.z, 32);
        a_o.w = __shfl_xor(acc.w, 32);
        float nm = fmaxf(m, m_o);
        float sa = (m == nm)   ? 1.f : __expf(m - nm);
        float sb = (m_o == nm) ? 1.f : __expf(m_o - nm);
        float sm = ssum * sa + s_o * sb;
        float4 am;
        am.x = acc.x * sa + a_o.x * sb;
        am.y = acc.y * sa + a_o.y * sb;
        am.z = acc.z * sa + a_o.z * sb;
        am.w = acc.w * sa + a_o.w * sb;

        float* dst = part + (size_t)cid * PSTRIDE;
        if (lane == 0) { dst[0] = nm; dst[1] = sm; }
        if (half == 0) *(float4*)(dst + 8 + sl * 4) = am;

        // release partial, count arrival; last wave of segment b combines
        __threadfence();
        int old = 0;
        if (lane == 0) old = atomicAdd(&done[b], 1);
        old = __shfl(old, 0);
        int cnt = s_pre[b + 1] - s_pre[b];
        if (old == cnt - 1) {
            __threadfence();                  // acquire all partials
            int c0 = s_pre[b];
            float M = -INFINITY;
            for (int k = 0; k < cnt; ++k)
                M = fmaxf(M, part[(size_t)(c0 + k) * PSTRIDE]);
            int d0 = lane * 2, d1 = d0 + 1;
            float S = 0.f, R0 = 0.f, R1 = 0.f;
            for (int k = 0; k < cnt; ++k) {
                const float* pe = part + (size_t)(c0 + k) * PSTRIDE;
                float mk = pe[0];
                float w = (mk == M) ? 1.f : __expf(mk - M);   // guards -inf - -inf
                S  += w * pe[1];
                R0 += w * pe[8 + d0];
                R1 += w * pe[8 + d1];
            }
            float inv = 1.f / (S + 1e-8f);
            float r0 = R0 * inv, r1 = R1 * inv;
            float hp0 = h[b * D + d0], hp1 = h[b * D + d1];

            if (IT == 2) {
                out[b * B2D + d0] = hp0;  out[b * B2D + d1] = hp1;      // q half
                out[b * B2D + D + d0] = r0; out[b * B2D + D + d1] = r1; // readout
            } else {
                // wave-local LDS exchange of h_prev / readout
                s_hx[wslot][d0] = hp0; s_hx[wslot][d1] = hp1;
                s_rx[wslot][d0] = r0;  s_rx[wslot][d1] = r1;
                __builtin_amdgcn_wave_barrier();
                asm volatile("s_waitcnt lgkmcnt(0)" ::: "memory");
                __builtin_amdgcn_wave_barrier();

                // LSTM cell: lane owns dims d0,d1 -> 8 gate rows
                float accA[4], accB[4];
                #pragma unroll
                for (int g = 0; g < 4; ++g) {
                    accA[g] = b_ih[d0 + g * D] + b_hh[d0 + g * D];
                    accB[g] = b_ih[d1 + g * D] + b_hh[d1 + g * D];
                }
                for (int k = 0; k < D; k += 4) {
                    float4 xh = *(const float4*)&s_hx[wslot][k];
                    float4 xr = *(const float4*)&s_rx[wslot][k];
                    #pragma unroll
                    for (int g = 0; g < 4; ++g) {
                        const float* wrA = w_ih + (size_t)(d0 + g * D) * B2D;
                        const float* whA = w_hh + (size_t)(d0 + g * D) * D;
                        float4 wa = *(const float4*)(wrA + k);
                        float4 wb2 = *(const float4*)(wrA + D + k);
                        float4 wc = *(const float4*)(whA + k);
                        accA[g] += wa.x * xh.x + wa.y * xh.y + wa.z * xh.z + wa.w * xh.w
                                 + wb2.x * xr.x + wb2.y * xr.y + wb2.z * xr.z + wb2.w * xr.w
                                 + wc.x * xh.x + wc.y * xh.y + wc.z * xh.z + wc.w * xh.w;
                        const float* wrB = w_ih + (size_t)(d1 + g * D) * B2D;
                        const float* whB = w_hh + (size_t)(d1 + g * D) * D;
                        float4 wd = *(const float4*)(wrB + k);
                        float4 we4 = *(const float4*)(wrB + D + k);
                        float4 wf = *(const float4*)(whB + k);
                        accB[g] += wd.x * xh.x + wd.y * xh.y + wd.z * xh.z + wd.w * xh.w
                                 + we4.x * xr.x + we4.y * xr.y + we4.z * xr.z + we4.w * xr.w
                                 + wf.x * xh.x + wf.y * xh.y + wf.z * xh.z + wf.w * xh.w;
                    }
                }
                #pragma unroll
                for (int j = 0; j < 2; ++j) {
                    int d = j ? d1 : d0;
                    float gi = j ? accB[0] : accA[0];
                    float gf = j ? accB[1] : accA[1];
                    float gg = j ? accB[2] : accA[2];
                    float go = j ? accB[3] : accA[3];
                    float si = 1.f / (1.f + expf(-gi));
                    float sf = 1.f / (1.f + expf(-gf));
                    float so = 1.f / (1.f + expf(-go));
                    float cn = sf * c[b * D + d] + si * tanhf(gg);
                    float hn = so * tanhf(cn);
                    c[b * D + d] = cn;
                    h[b * D + d] = hn;        // in-place: all b-chunks are done
                }
            }
        }
    }
}

extern "C" void kernel_launch(void* const* d_in, const int* in_sizes, int n_in,
                              void* d_out, int out_size, void* d_ws, size_t ws_size,
                              hipStream_t stream) {
    const float* feat = (const float*)d_in[0];
    const int*   eb   = (const int*)d_in[1];
    const float* w_ih = (const float*)d_in[2];
    const float* w_hh = (const float*)d_in[3];
    const float* b_ih = (const float*)d_in[4];
    const float* b_hh = (const float*)d_in[5];
    float* out = (float*)d_out;
    float* ws  = (float*)d_ws;
    int E = in_sizes[1];   // 500000

    // workspace layout (float offsets)
    float* h    = ws;                        // 64*128
    float* c    = ws + NSEG * D;             // 64*128
    int*   seg  = (int*)(ws + 2 * NSEG * D); // 80
    int*   pre  = seg + 80;                  // 80
    int*   epw  = pre + 80;                  // 64
    int*   done = epw + 64;                  // 3*64
    float* part = ws + 2 * NSEG * D + 512;   // <=4096 chunks * 144 floats (~2.4 MB)

    k_setup<<<1, 128, 0, stream>>>(eb, E, b_ih, b_hh, seg, pre, epw, done, h, c);
    k_iter<0><<<NBLK, NTHR, 0, stream>>>(feat, w_ih, w_hh, b_ih, b_hh, seg, pre, epw,
                                         h, c, part, done, out);
    k_iter<1><<<NBLK, NTHR, 0, stream>>>(feat, w_ih, w_hh, b_ih, b_hh, seg, pre, epw,
                                         h, c, part, done + 64, out);
    k_iter<2><<<NBLK, NTHR, 0, stream>>>(feat, w_ih, w_hh, b_ih, b_hh, seg, pre, epw,
                                         h, c, part, done + 128, out);
}

// Round 5
// 524.744 us; speedup vs baseline: 2.0452x; 2.0452x over previous
//
#include <hip/hip_runtime.h>
#include <math.h>

#define D 128
#define B2D 256
#define NSEG 64
#define MAXC 512
#define PSTRIDE 144   // floats per chunk-partial: [0]=m, [1]=s, [8..135]=acc[128]
#define NBLK 2048
#define NTHR 256

// ---------------- setup: seg map (binary search, eb sorted) + chunk map +
// closed-form first LSTM step (q_star=h=c=0 => gates = b_ih+b_hh, same all rows)
__global__ __launch_bounds__(128) void k_setup(
        const int* __restrict__ eb, int E,
        const float* __restrict__ b_ih, const float* __restrict__ b_hh,
        int* __restrict__ seg, int* __restrict__ pre, int* __restrict__ epw,
        float* __restrict__ h, float* __restrict__ c) {
    __shared__ int s_seg[NSEG + 1], s_cnt[NSEG];
    int t = threadIdx.x;   // 0..127
    if (t <= NSEG) {
        int lo = 0, hi = E;
        while (lo < hi) { int mid = (lo + hi) >> 1; if (eb[mid] < t) lo = mid + 1; else hi = mid; }
        s_seg[t] = lo; seg[t] = lo;
    }
    __syncthreads();
    if (t < NSEG) {
        int len = s_seg[t + 1] - s_seg[t];
        int e = 64;                           // multiple of 8: full chunks have no tail
        int cc = (len + e - 1) / e;
        if (cc > MAXC) {                      // huge-segment fallback, keep e % 8 == 0
            e = (((len + MAXC - 1) / MAXC) + 7) & ~7;
            cc = (len + e - 1) / e;
        }
        if (len == 0) cc = 0;
        epw[t] = e; s_cnt[t] = cc;
    }
    __syncthreads();
    if (t == 0) {
        int a = 0;
        for (int j = 0; j < NSEG; ++j) { pre[j] = a; a += s_cnt[j]; }
        pre[NSEG] = a;
    }
    // closed-form LSTM step 1 (per feature dim t)
    float gi = b_ih[t] + b_hh[t];
    float gg = b_ih[t + 2 * D] + b_hh[t + 2 * D];
    float go = b_ih[t + 3 * D] + b_hh[t + 3 * D];
    float si = 1.f / (1.f + expf(-gi));
    float so = 1.f / (1.f + expf(-go));
    float cn = si * tanhf(gg);                // sigmoid(f)*c0 drops (c0=0)
    float hn = so * tanhf(cn);
    for (int b = 0; b < NSEG; ++b) { h[b * D + t] = hn; c[b * D + t] = cn; }
}

// ---------------- fused single-pass: logits + online softmax + weighted accumulate
// One wave per chunk. 8 edges per wave-iteration (4 per half-wave): 4 KB in
// flight, 4 independent shuffle-reduce chains, one softmax rescale per 8 edges.
__global__ __launch_bounds__(NTHR) void k_pass(
        const float* __restrict__ feat, const int* __restrict__ seg_ofs,
        const int* __restrict__ pre, const int* __restrict__ epw,
        const float* __restrict__ h, float* __restrict__ part) {
    __shared__ int s_pre[NSEG + 1], s_ofs[NSEG + 1], s_epw[NSEG];
    int tid = threadIdx.x;
    if (tid <= NSEG) { s_pre[tid] = pre[tid]; s_ofs[tid] = seg_ofs[tid]; }
    if (tid < NSEG) s_epw[tid] = epw[tid];
    __syncthreads();
    int total = s_pre[NSEG];
    int wave = (blockIdx.x * NTHR + tid) >> 6;
    int nwaves = (gridDim.x * NTHR) >> 6;
    int lane = tid & 63, half = lane >> 5, sl = lane & 31;

    for (int cid = wave; cid < total; cid += nwaves) {
        // binary search: largest b with s_pre[b] <= cid
        int lo = 0, hi = NSEG - 1;
        while (lo < hi) {
            int mid = (lo + hi + 1) >> 1;
            if (s_pre[mid] <= cid) lo = mid; else hi = mid - 1;
        }
        int b = lo;
        int e = s_epw[b];
        long s0 = (long)s_ofs[b] + (long)(cid - s_pre[b]) * e;
        long s1 = (long)s_ofs[b + 1];
        long send = s0 + e;
        if (send < s1) s1 = send;

        float4 q4 = *(const float4*)(h + (size_t)b * D + sl * 4);
        float m = -INFINITY, ssum = 0.f;
        float4 acc = make_float4(0.f, 0.f, 0.f, 0.f);

        long n8 = (s1 - s0) >> 3;             // 8-edge groups
        long ee = s0 + n8 * 8;

        if (n8 > 0) {
            // half-wave hw handles edges g*8 + hw*4 + {0..3}
            const float* p = feat + (size_t)(s0 + half * 4) * D + sl * 4;
            float4 f0 = *(const float4*)(p);
            float4 f1 = *(const float4*)(p + D);
            float4 f2 = *(const float4*)(p + 2 * D);
            float4 f3 = *(const float4*)(p + 3 * D);
            p += 8 * D;
            for (long g = 0; g < n8; ++g) {
                float4 c0 = f0, c1 = f1, c2 = f2, c3 = f3;
                if (g + 1 < n8) {             // prefetch next group (4 KB/wave in flight)
                    f0 = *(const float4*)(p);
                    f1 = *(const float4*)(p + D);
                    f2 = *(const float4*)(p + 2 * D);
                    f3 = *(const float4*)(p + 3 * D);
                    p += 8 * D;
                }
                float p0 = c0.x * q4.x + c0.y * q4.y + c0.z * q4.z + c0.w * q4.w;
                float p1 = c1.x * q4.x + c1.y * q4.y + c1.z * q4.z + c1.w * q4.w;
                float p2 = c2.x * q4.x + c2.y * q4.y + c2.z * q4.z + c2.w * q4.w;
                float p3 = c3.x * q4.x + c3.y * q4.y + c3.z * q4.z + c3.w * q4.w;
                // 4 independent 5-level reduce chains (pipeline in the LDS pipe)
                p0 += __shfl_xor(p0, 16, 32); p1 += __shfl_xor(p1, 16, 32);
                p2 += __shfl_xor(p2, 16, 32); p3 += __shfl_xor(p3, 16, 32);
                p0 += __shfl_xor(p0, 8, 32);  p1 += __shfl_xor(p1, 8, 32);
                p2 += __shfl_xor(p2, 8, 32);  p3 += __shfl_xor(p3, 8, 32);
                p0 += __shfl_xor(p0, 4, 32);  p1 += __shfl_xor(p1, 4, 32);
                p2 += __shfl_xor(p2, 4, 32);  p3 += __shfl_xor(p3, 4, 32);
                p0 += __shfl_xor(p0, 2, 32);  p1 += __shfl_xor(p1, 2, 32);
                p2 += __shfl_xor(p2, 2, 32);  p3 += __shfl_xor(p3, 2, 32);
                p0 += __shfl_xor(p0, 1, 32);  p1 += __shfl_xor(p1, 1, 32);
                p2 += __shfl_xor(p2, 1, 32);  p3 += __shfl_xor(p3, 1, 32);
                float mx = fmaxf(fmaxf(p0, p1), fmaxf(p2, p3));
                float nm = fmaxf(m, mx);
                float sc = __expf(m - nm);    // exp(-inf)=0 on first group
                float w0 = __expf(p0 - nm), w1 = __expf(p1 - nm);
                float w2 = __expf(p2 - nm), w3 = __expf(p3 - nm);
                ssum = ssum * sc + ((w0 + w1) + (w2 + w3));
                acc.x = acc.x * sc + ((w0 * c0.x + w1 * c1.x) + (w2 * c2.x + w3 * c3.x));
                acc.y = acc.y * sc + ((w0 * c0.y + w1 * c1.y) + (w2 * c2.y + w3 * c3.y));
                acc.z = acc.z * sc + ((w0 * c0.z + w1 * c1.z) + (w2 * c2.z + w3 * c3.z));
                acc.w = acc.w * sc + ((w0 * c0.w + w1 * c1.w) + (w2 * c2.w + w3 * c3.w));
                m = nm;
            }
        }

        // tail: 0..7 edges, 2-wide masked
        for (; ee < s1; ee += 2) {
            long my_e = ee + half;
            bool valid = my_e < s1;
            float4 f4 = make_float4(0.f, 0.f, 0.f, 0.f);
            if (valid) f4 = *(const float4*)(feat + (size_t)my_e * D + sl * 4);
            float p = f4.x * q4.x + f4.y * q4.y + f4.z * q4.z + f4.w * q4.w;
            p += __shfl_xor(p, 16, 32);
            p += __shfl_xor(p, 8, 32);
            p += __shfl_xor(p, 4, 32);
            p += __shfl_xor(p, 2, 32);
            p += __shfl_xor(p, 1, 32);
            if (valid) {
                float nm = fmaxf(m, p);
                float sc = __expf(m - nm);
                float we = __expf(p - nm);
                ssum = ssum * sc + we;
                acc.x = acc.x * sc + we * f4.x;
                acc.y = acc.y * sc + we * f4.y;
                acc.z = acc.z * sc + we * f4.z;
                acc.w = acc.w * sc + we * f4.w;
                m = nm;
            }
        }

        // merge the two half-wave states (a chunk always has >=1 edge => half0 finite)
        float m_o = __shfl_xor(m, 32);
        float s_o = __shfl_xor(ssum, 32);
        float4 a_o;
        a_o.x = __shfl_xor(acc.x, 32);
        a_o.y = __shfl_xor(acc.y, 32);
        a_o.z = __shfl_xor(acc.z, 32);
        a_o.w = __shfl_xor(acc.w, 32);
        float nm = fmaxf(m, m_o);
        float sa = (m == nm)   ? 1.f : __expf(m - nm);
        float sb = (m_o == nm) ? 1.f : __expf(m_o - nm);
        float sm = ssum * sa + s_o * sb;
        float4 am;
        am.x = acc.x * sa + a_o.x * sb;
        am.y = acc.y * sa + a_o.y * sb;
        am.z = acc.z * sa + a_o.z * sb;
        am.w = acc.w * sa + a_o.w * sb;

        float* dst = part + (size_t)cid * PSTRIDE;
        if (lane == 0) { dst[0] = nm; dst[1] = sm; }
        if (half == 0) *(float4*)(dst + 8 + sl * 4) = am;
    }
}

// ---------------- fused: combine chunk partials + next-iteration LSTM cell ----------------
// Block b owns segment/row b. Readout stays in smem. last=1: write final output.
__global__ __launch_bounds__(512) void k_comb_lstm(
        const float* __restrict__ part, const int* __restrict__ pre,
        const float* __restrict__ w_ih, const float* __restrict__ w_hh,
        const float* __restrict__ b_ih, const float* __restrict__ b_hh,
        float* __restrict__ h, float* __restrict__ c,
        float* __restrict__ out, int last) {
    int b = blockIdx.x, t = threadIdx.x;   // t: 0..511
    int c0 = pre[b], nc = pre[b + 1] - c0;
    __shared__ float s_w[MAXC];
    __shared__ float red[512];
    __shared__ float s_r[D];    // readout
    __shared__ float s_h[D];    // h_prev (== q)
    __shared__ float s_g[4 * D];

    // pass 1: global max of chunk maxima
    float M = -INFINITY;
    for (int cc = t; cc < nc; cc += 512) M = fmaxf(M, part[(size_t)(c0 + cc) * PSTRIDE]);
    red[t] = M; __syncthreads();
    for (int o = 256; o > 0; o >>= 1) {
        if (t < o) red[t] = fmaxf(red[t], red[t + o]);
        __syncthreads();
    }
    M = red[0]; __syncthreads();

    // pass 2: per-chunk weights + rescaled sum
    float S = 0.f;
    for (int cc = t; cc < nc; cc += 512) {
        const float* pe = part + (size_t)(c0 + cc) * PSTRIDE;
        float w = __expf(pe[0] - M);
        s_w[cc] = w;
        S += w * pe[1];
    }
    red[t] = S; __syncthreads();
    for (int o = 256; o > 0; o >>= 1) {
        if (t < o) red[t] += red[t + o];
        __syncthreads();
    }
    S = red[0]; __syncthreads();

    // pass 3: rescaled accumulator; 4 thread-groups split the chunk loop
    int d = t & (D - 1), j = t >> 7;
    float R = 0.f;
    for (int cc = j; cc < nc; cc += 4)
        R += s_w[cc] * part[(size_t)(c0 + cc) * PSTRIDE + 8 + d];
    red[t] = R; __syncthreads();
    if (t < 256) red[t] += red[t + 256];
    __syncthreads();
    if (t < D) {
        float r = (red[t] + red[t + 128]) / (S + 1e-8f);
        s_r[t] = r;
        s_h[t] = h[b * D + t];
        if (last) { out[b * B2D + D + t] = r; out[b * B2D + t] = s_h[t]; }
    }
    __syncthreads();
    if (last) return;

    // LSTM cell for the next iteration: x = [h_prev, readout], h = h_prev
    float acc = b_ih[t] + b_hh[t];
    const float* wr = w_ih + (size_t)t * B2D;
    #pragma unroll 8
    for (int k = 0; k < D; k += 4) {
        float4 w4 = *(const float4*)(wr + k);
        acc += w4.x * s_h[k] + w4.y * s_h[k + 1] + w4.z * s_h[k + 2] + w4.w * s_h[k + 3];
    }
    #pragma unroll 8
    for (int k = 0; k < D; k += 4) {
        float4 w4 = *(const float4*)(wr + D + k);
        acc += w4.x * s_r[k] + w4.y * s_r[k + 1] + w4.z * s_r[k + 2] + w4.w * s_r[k + 3];
    }
    const float* wh = w_hh + (size_t)t * D;
    #pragma unroll 8
    for (int k = 0; k < D; k += 4) {
        float4 w4 = *(const float4*)(wh + k);
        acc += w4.x * s_h[k] + w4.y * s_h[k + 1] + w4.z * s_h[k + 2] + w4.w * s_h[k + 3];
    }
    s_g[t] = acc;
    __syncthreads();

    if (t < D) {
        float gi = s_g[t], gf = s_g[t + D], gg = s_g[t + 2 * D], go = s_g[t + 3 * D];
        float si = 1.f / (1.f + expf(-gi));
        float sf = 1.f / (1.f + expf(-gf));
        float so = 1.f / (1.f + expf(-go));
        float cn = sf * c[b * D + t] + si * tanhf(gg);
        float hn = so * tanhf(cn);
        c[b * D + t] = cn;
        h[b * D + t] = hn;
    }
}

extern "C" void kernel_launch(void* const* d_in, const int* in_sizes, int n_in,
                              void* d_out, int out_size, void* d_ws, size_t ws_size,
                              hipStream_t stream) {
    const float* feat = (const float*)d_in[0];
    const int*   eb   = (const int*)d_in[1];
    const float* w_ih = (const float*)d_in[2];
    const float* w_hh = (const float*)d_in[3];
    const float* b_ih = (const float*)d_in[4];
    const float* b_hh = (const float*)d_in[5];
    float* out = (float*)d_out;
    float* ws  = (float*)d_ws;
    int E = in_sizes[1];   // 500000

    // workspace layout (float offsets)
    float* h    = ws;                        // 64*128
    float* c    = ws + NSEG * D;             // 64*128
    int*   seg  = (int*)(ws + 2 * NSEG * D); // 80
    int*   pre  = seg + 80;                  // 80
    int*   epw  = pre + 80;                  // 64
    float* part = ws + 2 * NSEG * D + 512;   // <=~7900 chunks * 144 floats (~4.6 MB)

    k_setup<<<1, 128, 0, stream>>>(eb, E, b_ih, b_hh, seg, pre, epw, h, c);
    for (int it = 0; it < 3; ++it) {
        k_pass<<<NBLK, NTHR, 0, stream>>>(feat, seg, pre, epw, h, part);
        k_comb_lstm<<<NSEG, 512, 0, stream>>>(part, pre, w_ih, w_hh, b_ih, b_hh,
                                              h, c, out, it == 2);
    }
}

// Round 6
// 514.173 us; speedup vs baseline: 2.0873x; 1.0206x over previous
//
#include <hip/hip_runtime.h>
#include <math.h>

#define D 128
#define B2D 256
#define NSEG 64
#define MAXC 512
#define PSTRIDE 144   // floats per chunk-partial: [0]=m, [1]=s, [8..135]=acc[128]
#define NBLK 2048
#define NTHR 256

// round-to-nearest-even fp32 -> bf16, packed pair
__device__ __forceinline__ unsigned pack_bf16x2(float x, float y) {
    unsigned ux = __float_as_uint(x); ux = (ux + 0x7fffu + ((ux >> 16) & 1u)) >> 16;
    unsigned uy = __float_as_uint(y); uy = (uy + 0x7fffu + ((uy >> 16) & 1u)) >> 16;
    return ux | (uy << 16);
}
#define BLO(u) __uint_as_float((u) << 16)
#define BHI(u) __uint_as_float((u) & 0xffff0000u)

// ---------------- setup: seg map (binary search, eb sorted) + chunk map +
// closed-form first LSTM step (q_star=h=c=0 => gates = b_ih+b_hh, same all rows)
__global__ __launch_bounds__(128) void k_setup(
        const int* __restrict__ eb, int E,
        const float* __restrict__ b_ih, const float* __restrict__ b_hh,
        int* __restrict__ seg, int* __restrict__ pre, int* __restrict__ epw,
        float* __restrict__ h, float* __restrict__ c) {
    __shared__ int s_seg[NSEG + 1], s_cnt[NSEG];
    int t = threadIdx.x;   // 0..127
    if (t <= NSEG) {
        int lo = 0, hi = E;
        while (lo < hi) { int mid = (lo + hi) >> 1; if (eb[mid] < t) lo = mid + 1; else hi = mid; }
        s_seg[t] = lo; seg[t] = lo;
    }
    __syncthreads();
    if (t < NSEG) {
        int len = s_seg[t + 1] - s_seg[t];
        int e = 64;                           // multiple of 8: full chunks have no tail
        int cc = (len + e - 1) / e;
        if (cc > MAXC) {                      // huge-segment fallback, keep e % 8 == 0
            e = (((len + MAXC - 1) / MAXC) + 7) & ~7;
            cc = (len + e - 1) / e;
        }
        if (len == 0) cc = 0;
        epw[t] = e; s_cnt[t] = cc;
    }
    __syncthreads();
    if (t == 0) {
        int a = 0;
        for (int j = 0; j < NSEG; ++j) { pre[j] = a; a += s_cnt[j]; }
        pre[NSEG] = a;
    }
    // closed-form LSTM step 1 (per feature dim t)
    float gi = b_ih[t] + b_hh[t];
    float gg = b_ih[t + 2 * D] + b_hh[t + 2 * D];
    float go = b_ih[t + 3 * D] + b_hh[t + 3 * D];
    float si = 1.f / (1.f + expf(-gi));
    float so = 1.f / (1.f + expf(-go));
    float cn = si * tanhf(gg);                // sigmoid(f)*c0 drops (c0=0)
    float hn = so * tanhf(cn);
    for (int b = 0; b < NSEG; ++b) { h[b * D + t] = hn; c[b * D + t] = cn; }
}

// ---------------- fused single-pass: logits + online softmax + weighted accumulate
// One wave per chunk, 8 edges per wave-iteration (4 per half-wave), prefetched.
// MODE 0: read fp32 feat, and write the bf16 copy as we stream (iteration 1).
// MODE 1: read bf16 feat (128 MB, Infinity-Cache-resident) (iterations 2,3).
template <int MODE>
__global__ __launch_bounds__(NTHR) void k_pass(
        const float* __restrict__ feat, unsigned short* __restrict__ featb,
        const int* __restrict__ seg_ofs, const int* __restrict__ pre,
        const int* __restrict__ epw,
        const float* __restrict__ h, float* __restrict__ part) {
    __shared__ int s_pre[NSEG + 1], s_ofs[NSEG + 1], s_epw[NSEG];
    int tid = threadIdx.x;
    if (tid <= NSEG) { s_pre[tid] = pre[tid]; s_ofs[tid] = seg_ofs[tid]; }
    if (tid < NSEG) s_epw[tid] = epw[tid];
    __syncthreads();
    int total = s_pre[NSEG];
    int wave = (blockIdx.x * NTHR + tid) >> 6;
    int nwaves = (gridDim.x * NTHR) >> 6;
    int lane = tid & 63, half = lane >> 5, sl = lane & 31;

    for (int cid = wave; cid < total; cid += nwaves) {
        // binary search: largest b with s_pre[b] <= cid
        int lo = 0, hi = NSEG - 1;
        while (lo < hi) {
            int mid = (lo + hi + 1) >> 1;
            if (s_pre[mid] <= cid) lo = mid; else hi = mid - 1;
        }
        int b = lo;
        int e = s_epw[b];
        long s0 = (long)s_ofs[b] + (long)(cid - s_pre[b]) * e;
        long s1 = (long)s_ofs[b + 1];
        long send = s0 + e;
        if (send < s1) s1 = send;

        float4 q4 = *(const float4*)(h + (size_t)b * D + sl * 4);
        float m = -INFINITY, ssum = 0.f;
        float4 acc = make_float4(0.f, 0.f, 0.f, 0.f);

        long n8 = (s1 - s0) >> 3;             // 8-edge groups
        long ee = s0 + n8 * 8;

        if (n8 > 0) {
            float4 f0, f1, f2, f3;            // MODE 0 carries fp32 rows
            uint2  v0, v1, v2, v3;            // MODE 1 carries bf16 rows
            if (MODE == 0) {
                const float* p = feat + (size_t)(s0 + half * 4) * D + sl * 4;
                f0 = *(const float4*)(p);
                f1 = *(const float4*)(p + D);
                f2 = *(const float4*)(p + 2 * D);
                f3 = *(const float4*)(p + 3 * D);
                long row = s0 + half * 4;
                for (long g = 0; g < n8; ++g) {
                    float4 c0 = f0, c1 = f1, c2 = f2, c3 = f3;
                    if (g + 1 < n8) {
                        const float* pn = feat + (size_t)(row + 8) * D + sl * 4;
                        f0 = *(const float4*)(pn);
                        f1 = *(const float4*)(pn + D);
                        f2 = *(const float4*)(pn + 2 * D);
                        f3 = *(const float4*)(pn + 3 * D);
                    }
                    // write the bf16 copy of the 4 rows we own
                    {
                        uint2* wp = (uint2*)(featb + (size_t)row * D) + sl;
                        wp[0]  = make_uint2(pack_bf16x2(c0.x, c0.y), pack_bf16x2(c0.z, c0.w));
                        wp[32] = make_uint2(pack_bf16x2(c1.x, c1.y), pack_bf16x2(c1.z, c1.w));
                        wp[64] = make_uint2(pack_bf16x2(c2.x, c2.y), pack_bf16x2(c2.z, c2.w));
                        wp[96] = make_uint2(pack_bf16x2(c3.x, c3.y), pack_bf16x2(c3.z, c3.w));
                    }
                    row += 8;
                    float p0 = c0.x * q4.x + c0.y * q4.y + c0.z * q4.z + c0.w * q4.w;
                    float p1 = c1.x * q4.x + c1.y * q4.y + c1.z * q4.z + c1.w * q4.w;
                    float p2 = c2.x * q4.x + c2.y * q4.y + c2.z * q4.z + c2.w * q4.w;
                    float p3 = c3.x * q4.x + c3.y * q4.y + c3.z * q4.z + c3.w * q4.w;
                    p0 += __shfl_xor(p0, 16, 32); p1 += __shfl_xor(p1, 16, 32);
                    p2 += __shfl_xor(p2, 16, 32); p3 += __shfl_xor(p3, 16, 32);
                    p0 += __shfl_xor(p0, 8, 32);  p1 += __shfl_xor(p1, 8, 32);
                    p2 += __shfl_xor(p2, 8, 32);  p3 += __shfl_xor(p3, 8, 32);
                    p0 += __shfl_xor(p0, 4, 32);  p1 += __shfl_xor(p1, 4, 32);
                    p2 += __shfl_xor(p2, 4, 32);  p3 += __shfl_xor(p3, 4, 32);
                    p0 += __shfl_xor(p0, 2, 32);  p1 += __shfl_xor(p1, 2, 32);
                    p2 += __shfl_xor(p2, 2, 32);  p3 += __shfl_xor(p3, 2, 32);
                    p0 += __shfl_xor(p0, 1, 32);  p1 += __shfl_xor(p1, 1, 32);
                    p2 += __shfl_xor(p2, 1, 32);  p3 += __shfl_xor(p3, 1, 32);
                    float mx = fmaxf(fmaxf(p0, p1), fmaxf(p2, p3));
                    float nm = fmaxf(m, mx);
                    float sc = __expf(m - nm);
                    float w0 = __expf(p0 - nm), w1 = __expf(p1 - nm);
                    float w2 = __expf(p2 - nm), w3 = __expf(p3 - nm);
                    ssum = ssum * sc + ((w0 + w1) + (w2 + w3));
                    acc.x = acc.x * sc + ((w0 * c0.x + w1 * c1.x) + (w2 * c2.x + w3 * c3.x));
                    acc.y = acc.y * sc + ((w0 * c0.y + w1 * c1.y) + (w2 * c2.y + w3 * c3.y));
                    acc.z = acc.z * sc + ((w0 * c0.z + w1 * c1.z) + (w2 * c2.z + w3 * c3.z));
                    acc.w = acc.w * sc + ((w0 * c0.w + w1 * c1.w) + (w2 * c2.w + w3 * c3.w));
                    m = nm;
                }
            } else {
                const uint2* p = (const uint2*)(featb + (size_t)(s0 + half * 4) * D) + sl;
                v0 = p[0]; v1 = p[32]; v2 = p[64]; v3 = p[96];
                p += 256;                     // 8 rows * 32 uint2
                for (long g = 0; g < n8; ++g) {
                    uint2 u0 = v0, u1 = v1, u2 = v2, u3 = v3;
                    if (g + 1 < n8) { v0 = p[0]; v1 = p[32]; v2 = p[64]; v3 = p[96]; p += 256; }
                    float4 c0 = make_float4(BLO(u0.x), BHI(u0.x), BLO(u0.y), BHI(u0.y));
                    float4 c1 = make_float4(BLO(u1.x), BHI(u1.x), BLO(u1.y), BHI(u1.y));
                    float4 c2 = make_float4(BLO(u2.x), BHI(u2.x), BLO(u2.y), BHI(u2.y));
                    float4 c3 = make_float4(BLO(u3.x), BHI(u3.x), BLO(u3.y), BHI(u3.y));
                    float p0 = c0.x * q4.x + c0.y * q4.y + c0.z * q4.z + c0.w * q4.w;
                    float p1 = c1.x * q4.x + c1.y * q4.y + c1.z * q4.z + c1.w * q4.w;
                    float p2 = c2.x * q4.x + c2.y * q4.y + c2.z * q4.z + c2.w * q4.w;
                    float p3 = c3.x * q4.x + c3.y * q4.y + c3.z * q4.z + c3.w * q4.w;
                    p0 += __shfl_xor(p0, 16, 32); p1 += __shfl_xor(p1, 16, 32);
                    p2 += __shfl_xor(p2, 16, 32); p3 += __shfl_xor(p3, 16, 32);
                    p0 += __shfl_xor(p0, 8, 32);  p1 += __shfl_xor(p1, 8, 32);
                    p2 += __shfl_xor(p2, 8, 32);  p3 += __shfl_xor(p3, 8, 32);
                    p0 += __shfl_xor(p0, 4, 32);  p1 += __shfl_xor(p1, 4, 32);
                    p2 += __shfl_xor(p2, 4, 32);  p3 += __shfl_xor(p3, 4, 32);
                    p0 += __shfl_xor(p0, 2, 32);  p1 += __shfl_xor(p1, 2, 32);
                    p2 += __shfl_xor(p2, 2, 32);  p3 += __shfl_xor(p3, 2, 32);
                    p0 += __shfl_xor(p0, 1, 32);  p1 += __shfl_xor(p1, 1, 32);
                    p2 += __shfl_xor(p2, 1, 32);  p3 += __shfl_xor(p3, 1, 32);
                    float mx = fmaxf(fmaxf(p0, p1), fmaxf(p2, p3));
                    float nm = fmaxf(m, mx);
                    float sc = __expf(m - nm);
                    float w0 = __expf(p0 - nm), w1 = __expf(p1 - nm);
                    float w2 = __expf(p2 - nm), w3 = __expf(p3 - nm);
                    ssum = ssum * sc + ((w0 + w1) + (w2 + w3));
                    acc.x = acc.x * sc + ((w0 * c0.x + w1 * c1.x) + (w2 * c2.x + w3 * c3.x));
                    acc.y = acc.y * sc + ((w0 * c0.y + w1 * c1.y) + (w2 * c2.y + w3 * c3.y));
                    acc.z = acc.z * sc + ((w0 * c0.z + w1 * c1.z) + (w2 * c2.z + w3 * c3.z));
                    acc.w = acc.w * sc + ((w0 * c0.w + w1 * c1.w) + (w2 * c2.w + w3 * c3.w));
                    m = nm;
                }
            }
        }

        // tail: 0..7 edges, 2-wide masked
        for (; ee < s1; ee += 2) {
            long my_e = ee + half;
            bool valid = my_e < s1;
            float4 f4 = make_float4(0.f, 0.f, 0.f, 0.f);
            if (valid) {
                if (MODE == 0) {
                    f4 = *(const float4*)(feat + (size_t)my_e * D + sl * 4);
                    *((uint2*)(featb + (size_t)my_e * D) + sl) =
                        make_uint2(pack_bf16x2(f4.x, f4.y), pack_bf16x2(f4.z, f4.w));
                } else {
                    uint2 v = *((const uint2*)(featb + (size_t)my_e * D) + sl);
                    f4 = make_float4(BLO(v.x), BHI(v.x), BLO(v.y), BHI(v.y));
                }
            }
            float p = f4.x * q4.x + f4.y * q4.y + f4.z * q4.z + f4.w * q4.w;
            p += __shfl_xor(p, 16, 32);
            p += __shfl_xor(p, 8, 32);
            p += __shfl_xor(p, 4, 32);
            p += __shfl_xor(p, 2, 32);
            p += __shfl_xor(p, 1, 32);
            if (valid) {
                float nm = fmaxf(m, p);
                float sc = __expf(m - nm);
                float we = __expf(p - nm);
                ssum = ssum * sc + we;
                acc.x = acc.x * sc + we * f4.x;
                acc.y = acc.y * sc + we * f4.y;
                acc.z = acc.z * sc + we * f4.z;
                acc.w = acc.w * sc + we * f4.w;
                m = nm;
            }
        }

        // merge the two half-wave states (NaN-guarded)
        float m_o = __shfl_xor(m, 32);
        float s_o = __shfl_xor(ssum, 32);
        float4 a_o;
        a_o.x = __shfl_xor(acc.x, 32);
        a_o.y = __shfl_xor(acc.y, 32);
        a_o.z = __shfl_xor(acc.z, 32);
        a_o.w = __shfl_xor(acc.w, 32);
        float nm = fmaxf(m, m_o);
        float sa = (m == nm)   ? 1.f : __expf(m - nm);
        float sb = (m_o == nm) ? 1.f : __expf(m_o - nm);
        float sm = ssum * sa + s_o * sb;
        float4 am;
        am.x = acc.x * sa + a_o.x * sb;
        am.y = acc.y * sa + a_o.y * sb;
        am.z = acc.z * sa + a_o.z * sb;
        am.w = acc.w * sa + a_o.w * sb;

        float* dst = part + (size_t)cid * PSTRIDE;
        if (lane == 0) { dst[0] = nm; dst[1] = sm; }
        if (half == 0) *(float4*)(dst + 8 + sl * 4) = am;
    }
}

// ---------------- fused: combine chunk partials + next-iteration LSTM cell ----------------
__global__ __launch_bounds__(512) void k_comb_lstm(
        const float* __restrict__ part, const int* __restrict__ pre,
        const float* __restrict__ w_ih, const float* __restrict__ w_hh,
        const float* __restrict__ b_ih, const float* __restrict__ b_hh,
        float* __restrict__ h, float* __restrict__ c,
        float* __restrict__ out, int last) {
    int b = blockIdx.x, t = threadIdx.x;   // t: 0..511
    int c0 = pre[b], nc = pre[b + 1] - c0;
    __shared__ float s_w[MAXC];
    __shared__ float red[512];
    __shared__ float s_r[D];    // readout
    __shared__ float s_h[D];    // h_prev (== q)
    __shared__ float s_g[4 * D];

    // pass 1: global max of chunk maxima
    float M = -INFINITY;
    for (int cc = t; cc < nc; cc += 512) M = fmaxf(M, part[(size_t)(c0 + cc) * PSTRIDE]);
    red[t] = M; __syncthreads();
    for (int o = 256; o > 0; o >>= 1) {
        if (t < o) red[t] = fmaxf(red[t], red[t + o]);
        __syncthreads();
    }
    M = red[0]; __syncthreads();

    // pass 2: per-chunk weights + rescaled sum
    float S = 0.f;
    for (int cc = t; cc < nc; cc += 512) {
        const float* pe = part + (size_t)(c0 + cc) * PSTRIDE;
        float w = __expf(pe[0] - M);
        s_w[cc] = w;
        S += w * pe[1];
    }
    red[t] = S; __syncthreads();
    for (int o = 256; o > 0; o >>= 1) {
        if (t < o) red[t] += red[t + o];
        __syncthreads();
    }
    S = red[0]; __syncthreads();

    // pass 3: rescaled accumulator; 4 thread-groups split the chunk loop
    int d = t & (D - 1), j = t >> 7;
    float R = 0.f;
    for (int cc = j; cc < nc; cc += 4)
        R += s_w[cc] * part[(size_t)(c0 + cc) * PSTRIDE + 8 + d];
    red[t] = R; __syncthreads();
    if (t < 256) red[t] += red[t + 256];
    __syncthreads();
    if (t < D) {
        float r = (red[t] + red[t + 128]) / (S + 1e-8f);
        s_r[t] = r;
        s_h[t] = h[b * D + t];
        if (last) { out[b * B2D + D + t] = r; out[b * B2D + t] = s_h[t]; }
    }
    __syncthreads();
    if (last) return;

    // LSTM cell for the next iteration: x = [h_prev, readout], h = h_prev
    float acc = b_ih[t] + b_hh[t];
    const float* wr = w_ih + (size_t)t * B2D;
    #pragma unroll 8
    for (int k = 0; k < D; k += 4) {
        float4 w4 = *(const float4*)(wr + k);
        acc += w4.x * s_h[k] + w4.y * s_h[k + 1] + w4.z * s_h[k + 2] + w4.w * s_h[k + 3];
    }
    #pragma unroll 8
    for (int k = 0; k < D; k += 4) {
        float4 w4 = *(const float4*)(wr + D + k);
        acc += w4.x * s_r[k] + w4.y * s_r[k + 1] + w4.z * s_r[k + 2] + w4.w * s_r[k + 3];
    }
    const float* wh = w_hh + (size_t)t * D;
    #pragma unroll 8
    for (int k = 0; k < D; k += 4) {
        float4 w4 = *(const float4*)(wh + k);
        acc += w4.x * s_h[k] + w4.y * s_h[k + 1] + w4.z * s_h[k + 2] + w4.w * s_h[k + 3];
    }
    s_g[t] = acc;
    __syncthreads();

    if (t < D) {
        float gi = s_g[t], gf = s_g[t + D], gg = s_g[t + 2 * D], go = s_g[t + 3 * D];
        float si = 1.f / (1.f + expf(-gi));
        float sf = 1.f / (1.f + expf(-gf));
        float so = 1.f / (1.f + expf(-go));
        float cn = sf * c[b * D + t] + si * tanhf(gg);
        float hn = so * tanhf(cn);
        c[b * D + t] = cn;
        h[b * D + t] = hn;
    }
}

extern "C" void kernel_launch(void* const* d_in, const int* in_sizes, int n_in,
                              void* d_out, int out_size, void* d_ws, size_t ws_size,
                              hipStream_t stream) {
    const float* feat = (const float*)d_in[0];
    const int*   eb   = (const int*)d_in[1];
    const float* w_ih = (const float*)d_in[2];
    const float* w_hh = (const float*)d_in[3];
    const float* b_ih = (const float*)d_in[4];
    const float* b_hh = (const float*)d_in[5];
    float* out = (float*)d_out;
    float* ws  = (float*)d_ws;
    int E = in_sizes[1];   // 500000

    // workspace layout (float offsets)
    float* h    = ws;                        // 64*128
    float* c    = ws + NSEG * D;             // 64*128
    int*   seg  = (int*)(ws + 2 * NSEG * D); // 80
    int*   pre  = seg + 80;                  // 80
    int*   epw  = pre + 80;                  // 64
    unsigned short* featb = (unsigned short*)(ws + 16640);        // E*D bf16 (128 MB)
    size_t fb_floats = (((size_t)E * D / 2) + 3) & ~(size_t)3;
    float* part = ws + 16640 + fb_floats;    // <=~7900 chunks * 144 floats (~4.6 MB)

    k_setup<<<1, 128, 0, stream>>>(eb, E, b_ih, b_hh, seg, pre, epw, h, c);
    k_pass<0><<<NBLK, NTHR, 0, stream>>>(feat, featb, seg, pre, epw, h, part);
    k_comb_lstm<<<NSEG, 512, 0, stream>>>(part, pre, w_ih, w_hh, b_ih, b_hh, h, c, out, 0);
    k_pass<1><<<NBLK, NTHR, 0, stream>>>(feat, featb, seg, pre, epw, h, part);
    k_comb_lstm<<<NSEG, 512, 0, stream>>>(part, pre, w_ih, w_hh, b_ih, b_hh, h, c, out, 0);
    k_pass<1><<<NBLK, NTHR, 0, stream>>>(feat, featb, seg, pre, epw, h, part);
    k_comb_lstm<<<NSEG, 512, 0, stream>>>(part, pre, w_ih, w_hh, b_ih, b_hh, h, c, out, 1);
}

// Round 7
// 510.358 us; speedup vs baseline: 2.1029x; 1.0075x over previous
//
#include <hip/hip_runtime.h>
#include <math.h>

#define D 128
#define B2D 256
#define NSEG 64
#define MAXC 512
#define PSTRIDE 144   // floats per chunk-partial: [0]=m, [1]=s, [8..135]=acc[128]
#define NBLK 2048
#define NTHR 256

// round-to-nearest-even fp32 -> bf16, packed pair
__device__ __forceinline__ unsigned pack_bf16x2(float x, float y) {
    unsigned ux = __float_as_uint(x); ux = (ux + 0x7fffu + ((ux >> 16) & 1u)) >> 16;
    unsigned uy = __float_as_uint(y); uy = (uy + 0x7fffu + ((uy >> 16) & 1u)) >> 16;
    return ux | (uy << 16);
}
#define BLO(u) __uint_as_float((u) << 16)
#define BHI(u) __uint_as_float((u) & 0xffff0000u)

// closed-form LSTM step 1 for one feature dim (q_star=h=c=0 => gates = b_ih+b_hh)
__device__ __forceinline__ void lstm1_dim(const float* b_ih, const float* b_hh,
                                          int dim, float* hn_o, float* cn_o) {
    float gi = b_ih[dim] + b_hh[dim];
    float gg = b_ih[dim + 2 * D] + b_hh[dim + 2 * D];
    float go = b_ih[dim + 3 * D] + b_hh[dim + 3 * D];
    float si = 1.f / (1.f + expf(-gi));
    float so = 1.f / (1.f + expf(-go));
    float cn = si * tanhf(gg);                // sigmoid(f)*c0 drops (c0=0)
    float hn = so * tanhf(cn);
    *hn_o = hn; *cn_o = cn;
}

// ---------------- fused single-pass: logits + online softmax + weighted accumulate
// One wave per chunk, 8 edges per wave-iteration (4 per half-wave), prefetched.
// MODE 0 (iteration 1): builds the seg/chunk map in-block from sorted eb (block 0
//   publishes it), computes the closed-form q, reads fp32 feat, writes bf16 copy.
// MODE 1 (iterations 2,3): reads the published map + bf16 feat (L3-resident).
template <int MODE>
__global__ __launch_bounds__(NTHR) void k_pass(
        const float* __restrict__ feat, unsigned short* __restrict__ featb,
        const int* __restrict__ eb, int E,
        int* __restrict__ seg_g, int* __restrict__ pre_g, int* __restrict__ epw_g,
        const float* __restrict__ b_ih, const float* __restrict__ b_hh,
        const float* __restrict__ h, float* __restrict__ part) {
    __shared__ int s_pre[NSEG + 1], s_ofs[NSEG + 1], s_epw[NSEG], s_cnt[NSEG];
    int tid = threadIdx.x;
    if (MODE == 0) {
        // build the map locally (redundant per block, ~1-2us, L2-broadcast reads)
        if (tid <= NSEG) {
            int lo = 0, hi = E;
            while (lo < hi) { int mid = (lo + hi) >> 1; if (eb[mid] < tid) lo = mid + 1; else hi = mid; }
            s_ofs[tid] = lo;
        }
        __syncthreads();
        if (tid < NSEG) {
            int len = s_ofs[tid + 1] - s_ofs[tid];
            int e = 64;                       // multiple of 8: full chunks have no tail
            int cc = (len + e - 1) / e;
            if (cc > MAXC) {                  // huge-segment fallback, keep e % 8 == 0
                e = (((len + MAXC - 1) / MAXC) + 7) & ~7;
                cc = (len + e - 1) / e;
            }
            if (len == 0) cc = 0;
            s_epw[tid] = e; s_cnt[tid] = cc;
        }
        __syncthreads();
        if (tid == 0) {
            int a = 0;
            for (int j = 0; j < NSEG; ++j) { s_pre[j] = a; a += s_cnt[j]; }
            s_pre[NSEG] = a;
        }
        __syncthreads();
        if (blockIdx.x == 0) {                // publish for comb / later passes
            if (tid <= NSEG) { seg_g[tid] = s_ofs[tid]; pre_g[tid] = s_pre[tid]; }
            if (tid < NSEG) epw_g[tid] = s_epw[tid];
        }
    } else {
        if (tid <= NSEG) { s_pre[tid] = pre_g[tid]; s_ofs[tid] = seg_g[tid]; }
        if (tid < NSEG) s_epw[tid] = epw_g[tid];
        __syncthreads();
    }
    int total = s_pre[NSEG];
    int wave = (blockIdx.x * NTHR + tid) >> 6;
    int nwaves = (gridDim.x * NTHR) >> 6;
    int lane = tid & 63, half = lane >> 5, sl = lane & 31;

    // iteration-1 query is identical for all segments: closed-form, hoisted
    float4 q4c;
    if (MODE == 0) {
        float hn, cn;
        lstm1_dim(b_ih, b_hh, sl * 4 + 0, &hn, &cn); q4c.x = hn;
        lstm1_dim(b_ih, b_hh, sl * 4 + 1, &hn, &cn); q4c.y = hn;
        lstm1_dim(b_ih, b_hh, sl * 4 + 2, &hn, &cn); q4c.z = hn;
        lstm1_dim(b_ih, b_hh, sl * 4 + 3, &hn, &cn); q4c.w = hn;
    }

    for (int cid = wave; cid < total; cid += nwaves) {
        // binary search: largest b with s_pre[b] <= cid
        int lo = 0, hi = NSEG - 1;
        while (lo < hi) {
            int mid = (lo + hi + 1) >> 1;
            if (s_pre[mid] <= cid) lo = mid; else hi = mid - 1;
        }
        int b = lo;
        int e = s_epw[b];
        long s0 = (long)s_ofs[b] + (long)(cid - s_pre[b]) * e;
        long s1 = (long)s_ofs[b + 1];
        long send = s0 + e;
        if (send < s1) s1 = send;

        float4 q4 = (MODE == 0) ? q4c
                  : *(const float4*)(h + (size_t)b * D + sl * 4);
        float m = -INFINITY, ssum = 0.f;
        float4 acc = make_float4(0.f, 0.f, 0.f, 0.f);

        long n8 = (s1 - s0) >> 3;             // 8-edge groups
        long ee = s0 + n8 * 8;

        if (n8 > 0) {
            float4 f0, f1, f2, f3;            // MODE 0 carries fp32 rows
            uint2  v0, v1, v2, v3;            // MODE 1 carries bf16 rows
            if (MODE == 0) {
                const float* p = feat + (size_t)(s0 + half * 4) * D + sl * 4;
                f0 = *(const float4*)(p);
                f1 = *(const float4*)(p + D);
                f2 = *(const float4*)(p + 2 * D);
                f3 = *(const float4*)(p + 3 * D);
                long row = s0 + half * 4;
                for (long g = 0; g < n8; ++g) {
                    float4 c0 = f0, c1 = f1, c2 = f2, c3 = f3;
                    if (g + 1 < n8) {
                        const float* pn = feat + (size_t)(row + 8) * D + sl * 4;
                        f0 = *(const float4*)(pn);
                        f1 = *(const float4*)(pn + D);
                        f2 = *(const float4*)(pn + 2 * D);
                        f3 = *(const float4*)(pn + 3 * D);
                    }
                    // write the bf16 copy of the 4 rows we own
                    {
                        uint2* wp = (uint2*)(featb + (size_t)row * D) + sl;
                        wp[0]  = make_uint2(pack_bf16x2(c0.x, c0.y), pack_bf16x2(c0.z, c0.w));
                        wp[32] = make_uint2(pack_bf16x2(c1.x, c1.y), pack_bf16x2(c1.z, c1.w));
                        wp[64] = make_uint2(pack_bf16x2(c2.x, c2.y), pack_bf16x2(c2.z, c2.w));
                        wp[96] = make_uint2(pack_bf16x2(c3.x, c3.y), pack_bf16x2(c3.z, c3.w));
                    }
                    row += 8;
                    float p0 = c0.x * q4.x + c0.y * q4.y + c0.z * q4.z + c0.w * q4.w;
                    float p1 = c1.x * q4.x + c1.y * q4.y + c1.z * q4.z + c1.w * q4.w;
                    float p2 = c2.x * q4.x + c2.y * q4.y + c2.z * q4.z + c2.w * q4.w;
                    float p3 = c3.x * q4.x + c3.y * q4.y + c3.z * q4.z + c3.w * q4.w;
                    p0 += __shfl_xor(p0, 16, 32); p1 += __shfl_xor(p1, 16, 32);
                    p2 += __shfl_xor(p2, 16, 32); p3 += __shfl_xor(p3, 16, 32);
                    p0 += __shfl_xor(p0, 8, 32);  p1 += __shfl_xor(p1, 8, 32);
                    p2 += __shfl_xor(p2, 8, 32);  p3 += __shfl_xor(p3, 8, 32);
                    p0 += __shfl_xor(p0, 4, 32);  p1 += __shfl_xor(p1, 4, 32);
                    p2 += __shfl_xor(p2, 4, 32);  p3 += __shfl_xor(p3, 4, 32);
                    p0 += __shfl_xor(p0, 2, 32);  p1 += __shfl_xor(p1, 2, 32);
                    p2 += __shfl_xor(p2, 2, 32);  p3 += __shfl_xor(p3, 2, 32);
                    p0 += __shfl_xor(p0, 1, 32);  p1 += __shfl_xor(p1, 1, 32);
                    p2 += __shfl_xor(p2, 1, 32);  p3 += __shfl_xor(p3, 1, 32);
                    float mx = fmaxf(fmaxf(p0, p1), fmaxf(p2, p3));
                    float nm = fmaxf(m, mx);
                    float sc = __expf(m - nm);
                    float w0 = __expf(p0 - nm), w1 = __expf(p1 - nm);
                    float w2 = __expf(p2 - nm), w3 = __expf(p3 - nm);
                    ssum = ssum * sc + ((w0 + w1) + (w2 + w3));
                    acc.x = acc.x * sc + ((w0 * c0.x + w1 * c1.x) + (w2 * c2.x + w3 * c3.x));
                    acc.y = acc.y * sc + ((w0 * c0.y + w1 * c1.y) + (w2 * c2.y + w3 * c3.y));
                    acc.z = acc.z * sc + ((w0 * c0.z + w1 * c1.z) + (w2 * c2.z + w3 * c3.z));
                    acc.w = acc.w * sc + ((w0 * c0.w + w1 * c1.w) + (w2 * c2.w + w3 * c3.w));
                    m = nm;
                }
            } else {
                const uint2* p = (const uint2*)(featb + (size_t)(s0 + half * 4) * D) + sl;
                v0 = p[0]; v1 = p[32]; v2 = p[64]; v3 = p[96];
                p += 256;                     // 8 rows * 32 uint2
                for (long g = 0; g < n8; ++g) {
                    uint2 u0 = v0, u1 = v1, u2 = v2, u3 = v3;
                    if (g + 1 < n8) { v0 = p[0]; v1 = p[32]; v2 = p[64]; v3 = p[96]; p += 256; }
                    float4 c0 = make_float4(BLO(u0.x), BHI(u0.x), BLO(u0.y), BHI(u0.y));
                    float4 c1 = make_float4(BLO(u1.x), BHI(u1.x), BLO(u1.y), BHI(u1.y));
                    float4 c2 = make_float4(BLO(u2.x), BHI(u2.x), BLO(u2.y), BHI(u2.y));
                    float4 c3 = make_float4(BLO(u3.x), BHI(u3.x), BLO(u3.y), BHI(u3.y));
                    float p0 = c0.x * q4.x + c0.y * q4.y + c0.z * q4.z + c0.w * q4.w;
                    float p1 = c1.x * q4.x + c1.y * q4.y + c1.z * q4.z + c1.w * q4.w;
                    float p2 = c2.x * q4.x + c2.y * q4.y + c2.z * q4.z + c2.w * q4.w;
                    float p3 = c3.x * q4.x + c3.y * q4.y + c3.z * q4.z + c3.w * q4.w;
                    p0 += __shfl_xor(p0, 16, 32); p1 += __shfl_xor(p1, 16, 32);
                    p2 += __shfl_xor(p2, 16, 32); p3 += __shfl_xor(p3, 16, 32);
                    p0 += __shfl_xor(p0, 8, 32);  p1 += __shfl_xor(p1, 8, 32);
                    p2 += __shfl_xor(p2, 8, 32);  p3 += __shfl_xor(p3, 8, 32);
                    p0 += __shfl_xor(p0, 4, 32);  p1 += __shfl_xor(p1, 4, 32);
                    p2 += __shfl_xor(p2, 4, 32);  p3 += __shfl_xor(p3, 4, 32);
                    p0 += __shfl_xor(p0, 2, 32);  p1 += __shfl_xor(p1, 2, 32);
                    p2 += __shfl_xor(p2, 2, 32);  p3 += __shfl_xor(p3, 2, 32);
                    p0 += __shfl_xor(p0, 1, 32);  p1 += __shfl_xor(p1, 1, 32);
                    p2 += __shfl_xor(p2, 1, 32);  p3 += __shfl_xor(p3, 1, 32);
                    float mx = fmaxf(fmaxf(p0, p1), fmaxf(p2, p3));
                    float nm = fmaxf(m, mx);
                    float sc = __expf(m - nm);
                    float w0 = __expf(p0 - nm), w1 = __expf(p1 - nm);
                    float w2 = __expf(p2 - nm), w3 = __expf(p3 - nm);
                    ssum = ssum * sc + ((w0 + w1) + (w2 + w3));
                    acc.x = acc.x * sc + ((w0 * c0.x + w1 * c1.x) + (w2 * c2.x + w3 * c3.x));
                    acc.y = acc.y * sc + ((w0 * c0.y + w1 * c1.y) + (w2 * c2.y + w3 * c3.y));
                    acc.z = acc.z * sc + ((w0 * c0.z + w1 * c1.z) + (w2 * c2.z + w3 * c3.z));
                    acc.w = acc.w * sc + ((w0 * c0.w + w1 * c1.w) + (w2 * c2.w + w3 * c3.w));
                    m = nm;
                }
            }
        }

        // tail: 0..7 edges, 2-wide masked
        for (; ee < s1; ee += 2) {
            long my_e = ee + half;
            bool valid = my_e < s1;
            float4 f4 = make_float4(0.f, 0.f, 0.f, 0.f);
            if (valid) {
                if (MODE == 0) {
                    f4 = *(const float4*)(feat + (size_t)my_e * D + sl * 4);
                    *((uint2*)(featb + (size_t)my_e * D) + sl) =
                        make_uint2(pack_bf16x2(f4.x, f4.y), pack_bf16x2(f4.z, f4.w));
                } else {
                    uint2 v = *((const uint2*)(featb + (size_t)my_e * D) + sl);
                    f4 = make_float4(BLO(v.x), BHI(v.x), BLO(v.y), BHI(v.y));
                }
            }
            float p = f4.x * q4.x + f4.y * q4.y + f4.z * q4.z + f4.w * q4.w;
            p += __shfl_xor(p, 16, 32);
            p += __shfl_xor(p, 8, 32);
            p += __shfl_xor(p, 4, 32);
            p += __shfl_xor(p, 2, 32);
            p += __shfl_xor(p, 1, 32);
            if (valid) {
                float nm = fmaxf(m, p);
                float sc = __expf(m - nm);
                float we = __expf(p - nm);
                ssum = ssum * sc + we;
                acc.x = acc.x * sc + we * f4.x;
                acc.y = acc.y * sc + we * f4.y;
                acc.z = acc.z * sc + we * f4.z;
                acc.w = acc.w * sc + we * f4.w;
                m = nm;
            }
        }

        // merge the two half-wave states (NaN-guarded)
        float m_o = __shfl_xor(m, 32);
        float s_o = __shfl_xor(ssum, 32);
        float4 a_o;
        a_o.x = __shfl_xor(acc.x, 32);
        a_o.y = __shfl_xor(acc.y, 32);
        a_o.z = __shfl_xor(acc.z, 32);
        a_o.w = __shfl_xor(acc.w, 32);
        float nm = fmaxf(m, m_o);
        float sa = (m == nm)   ? 1.f : __expf(m - nm);
        float sb = (m_o == nm) ? 1.f : __expf(m_o - nm);
        float sm = ssum * sa + s_o * sb;
        float4 am;
        am.x = acc.x * sa + a_o.x * sb;
        am.y = acc.y * sa + a_o.y * sb;
        am.z = acc.z * sa + a_o.z * sb;
        am.w = acc.w * sa + a_o.w * sb;

        float* dst = part + (size_t)cid * PSTRIDE;
        if (lane == 0) { dst[0] = nm; dst[1] = sm; }
        if (half == 0) *(float4*)(dst + 8 + sl * 4) = am;
    }
}

// ---------------- fused: combine chunk partials + next-iteration LSTM cell ----------------
// Block b owns segment/row b. FIRST=1: h_prev/c_prev from the closed-form step-1
// values (h/c never read). LAST=1: write final output instead of running the LSTM.
template <int FIRST, int LAST>
__global__ __launch_bounds__(512) void k_comb_lstm(
        const float* __restrict__ part, const int* __restrict__ pre,
        const float* __restrict__ w_ih, const float* __restrict__ w_hh,
        const float* __restrict__ b_ih, const float* __restrict__ b_hh,
        float* __restrict__ h, float* __restrict__ c,
        float* __restrict__ out) {
    int b = blockIdx.x, t = threadIdx.x;   // t: 0..511
    int c0 = pre[b], nc = pre[b + 1] - c0;
    __shared__ float s_w[MAXC];
    __shared__ float red[512];
    __shared__ float s_r[D];    // readout
    __shared__ float s_h[D];    // h_prev (== q)
    __shared__ float s_g[4 * D];

    // pass 1: global max of chunk maxima
    float M = -INFINITY;
    for (int cc = t; cc < nc; cc += 512) M = fmaxf(M, part[(size_t)(c0 + cc) * PSTRIDE]);
    red[t] = M; __syncthreads();
    for (int o = 256; o > 0; o >>= 1) {
        if (t < o) red[t] = fmaxf(red[t], red[t + o]);
        __syncthreads();
    }
    M = red[0]; __syncthreads();

    // pass 2: per-chunk weights + rescaled sum
    float S = 0.f;
    for (int cc = t; cc < nc; cc += 512) {
        const float* pe = part + (size_t)(c0 + cc) * PSTRIDE;
        float w = __expf(pe[0] - M);
        s_w[cc] = w;
        S += w * pe[1];
    }
    red[t] = S; __syncthreads();
    for (int o = 256; o > 0; o >>= 1) {
        if (t < o) red[t] += red[t + o];
        __syncthreads();
    }
    S = red[0]; __syncthreads();

    // pass 3: rescaled accumulator; 4 thread-groups split the chunk loop
    int d = t & (D - 1), j = t >> 7;
    float R = 0.f;
    for (int cc = j; cc < nc; cc += 4)
        R += s_w[cc] * part[(size_t)(c0 + cc) * PSTRIDE + 8 + d];
    red[t] = R; __syncthreads();
    if (t < 256) red[t] += red[t + 256];
    __syncthreads();
    if (t < D) {
        float r = (red[t] + red[t + 128]) / (S + 1e-8f);
        s_r[t] = r;
        float hp, cp;
        if (FIRST) { lstm1_dim(b_ih, b_hh, t, &hp, &cp); }
        else       { hp = h[b * D + t]; }
        s_h[t] = hp;
        if (LAST) { out[b * B2D + D + t] = r; out[b * B2D + t] = hp; }
    }
    __syncthreads();
    if (LAST) return;

    // LSTM cell for the next iteration: x = [h_prev, readout], h = h_prev
    float acc = b_ih[t] + b_hh[t];
    const float* wr = w_ih + (size_t)t * B2D;
    #pragma unroll 8
    for (int k = 0; k < D; k += 4) {
        float4 w4 = *(const float4*)(wr + k);
        acc += w4.x * s_h[k] + w4.y * s_h[k + 1] + w4.z * s_h[k + 2] + w4.w * s_h[k + 3];
    }
    #pragma unroll 8
    for (int k = 0; k < D; k += 4) {
        float4 w4 = *(const float4*)(wr + D + k);
        acc += w4.x * s_r[k] + w4.y * s_r[k + 1] + w4.z * s_r[k + 2] + w4.w * s_r[k + 3];
    }
    const float* wh = w_hh + (size_t)t * D;
    #pragma unroll 8
    for (int k = 0; k < D; k += 4) {
        float4 w4 = *(const float4*)(wh + k);
        acc += w4.x * s_h[k] + w4.y * s_h[k + 1] + w4.z * s_h[k + 2] + w4.w * s_h[k + 3];
    }
    s_g[t] = acc;
    __syncthreads();

    if (t < D) {
        float gi = s_g[t], gf = s_g[t + D], gg = s_g[t + 2 * D], go = s_g[t + 3 * D];
        float si = 1.f / (1.f + expf(-gi));
        float sf = 1.f / (1.f + expf(-gf));
        float so = 1.f / (1.f + expf(-go));
        float cp;
        if (FIRST) { float hp_; lstm1_dim(b_ih, b_hh, t, &hp_, &cp); }
        else       { cp = c[b * D + t]; }
        float cn = sf * cp + si * tanhf(gg);
        float hn = so * tanhf(cn);
        c[b * D + t] = cn;
        h[b * D + t] = hn;
    }
}

extern "C" void kernel_launch(void* const* d_in, const int* in_sizes, int n_in,
                              void* d_out, int out_size, void* d_ws, size_t ws_size,
                              hipStream_t stream) {
    const float* feat = (const float*)d_in[0];
    const int*   eb   = (const int*)d_in[1];
    const float* w_ih = (const float*)d_in[2];
    const float* w_hh = (const float*)d_in[3];
    const float* b_ih = (const float*)d_in[4];
    const float* b_hh = (const float*)d_in[5];
    float* out = (float*)d_out;
    float* ws  = (float*)d_ws;
    int E = in_sizes[1];   // 500000

    // workspace layout (float offsets)
    float* h    = ws;                        // 64*128
    float* c    = ws + NSEG * D;             // 64*128
    int*   seg  = (int*)(ws + 2 * NSEG * D); // 80
    int*   pre  = seg + 80;                  // 80
    int*   epw  = pre + 80;                  // 64
    unsigned short* featb = (unsigned short*)(ws + 16640);        // E*D bf16 (128 MB)
    size_t fb_floats = (((size_t)E * D / 2) + 3) & ~(size_t)3;
    float* part = ws + 16640 + fb_floats;    // <=~7900 chunks * 144 floats (~4.6 MB)

    k_pass<0><<<NBLK, NTHR, 0, stream>>>(feat, featb, eb, E, seg, pre, epw,
                                         b_ih, b_hh, h, part);
    k_comb_lstm<1, 0><<<NSEG, 512, 0, stream>>>(part, pre, w_ih, w_hh, b_ih, b_hh,
                                                h, c, out);
    k_pass<1><<<NBLK, NTHR, 0, stream>>>(feat, featb, eb, E, seg, pre, epw,
                                         b_ih, b_hh, h, part);
    k_comb_lstm<0, 0><<<NSEG, 512, 0, stream>>>(part, pre, w_ih, w_hh, b_ih, b_hh,
                                                h, c, out);
    k_pass<1><<<NBLK, NTHR, 0, stream>>>(feat, featb, eb, E, seg, pre, epw,
                                         b_ih, b_hh, h, part);
    k_comb_lstm<0, 1><<<NSEG, 512, 0, stream>>>(part, pre, w_ih, w_hh, b_ih, b_hh,
                                                h, c, out);
}